// Round 2
// baseline (386.732 us; speedup 1.0000x reference)
//
#include <hip/hip_runtime.h>
#include <hip/hip_bf16.h>

#define B_N   256
#define IC_N  1152
#define J_N   10
#define D_N   16

// packed bf16 pair (in a dword) -> fp32
__device__ __forceinline__ float bf_lo(unsigned int u){
  union { unsigned int i; float f; } c; c.i = u << 16; return c.f;
}
__device__ __forceinline__ float bf_hi(unsigned int u){
  union { unsigned int i; float f; } c; c.i = u & 0xffff0000u; return c.f;
}
// fp32 -> bf16 (round-to-nearest-even), returned in low 16 bits
__device__ __forceinline__ unsigned int rne_hi16(float f){
  union { float ff; unsigned int i; } c; c.ff = f;
  return (c.i + 0x7FFFu + ((c.i >> 16) & 1u)) >> 16;
}

// prep: W fp32 -> packed bf16 pairs in ws; zero the s/vsum scratch.
// grid 2880 x 256 = 737280 threads = one per W element-pair.
__global__ __launch_bounds__(256) void caps_prep(
    const float* __restrict__ W, unsigned int* __restrict__ wbf,
    float* __restrict__ zero_region)
{
  const int t = blockIdx.x * 256 + threadIdx.x;            // 0..737279
  if (t < 2 * B_N * J_N * D_N) zero_region[t] = 0.f;       // s + vsum (81920 floats)
  const float2 p = ((const float2*)W)[t];                  // elements 2t, 2t+1 (e-pairs)
  wbf[t] = rne_hi16(p.x) | (rne_hi16(p.y) << 16);
}

// Pass kernel: one routing round, u_hat regenerated in registers.
// grid (64 b-groups, 9 i-chunks), block 320 = (j = tid/32) x (lane = i%32).
// W[j,i] held as packed bf16 in 64 VGPRs, reused across 4 batches.
__global__ __launch_bounds__(320, 2) void caps_pass(
    const float* __restrict__ x,          // inputs fp32 [B][IC][8]
    const unsigned int* __restrict__ wq,  // W packed bf16 [J][IC][64 dw]
    float* __restrict__ s_glob,           // [B][J][D] fp32 (atomic accum, pre-zeroed)
    const float* __restrict__ vsum,       // [B][J][D] running sum of v's
    const int round)
{
  __shared__ float ccx[16][32][11];   // softmax exchange, one slot per (it,bt)
  __shared__ float vsh[640];          // vsum staged for this block's 4 batches

  const int tid  = threadIdx.x;
  const int j    = tid >> 5;          // 0..9
  const int lane = tid & 31;
  const int b0   = blockIdx.x << 2;
  const int chunk= blockIdx.y;        // 0..8, 128 i's each

  if (round > 0) {
    for (int q = tid; q < 640; q += 320)
      vsh[q] = vsum[b0 * (J_N * D_N) + q];
    __syncthreads();
  }

  float s_acc[4][16];
  #pragma unroll
  for (int bt = 0; bt < 4; ++bt)
    #pragma unroll
    for (int d = 0; d < 16; ++d) s_acc[bt][d] = 0.f;

  for (int it = 0; it < 4; ++it) {
    const int i = chunk * 128 + it * 32 + lane;
    const uint4* wp = (const uint4*)(wq + ((size_t)(j * IC_N + i) << 6));
    uint4 w[16];                      // W[j,i]: 16 rows (d) x 8 bf16 (e)
    #pragma unroll
    for (int q = 0; q < 16; ++q) w[q] = wp[q];

    #pragma unroll
    for (int bt = 0; bt < 4; ++bt) {
      const int b = b0 + bt;
      const float4* xp = (const float4*)(x + ((size_t)(b * IC_N + i) << 3));
      const float4 xa = xp[0], xb = xp[1];
      const float x0 = xa.x, x1 = xa.y, x2 = xa.z, x3 = xa.w,
                  x4 = xb.x, x5 = xb.y, x6 = xb.z, x7 = xb.w;
      float uh[16];
      #pragma unroll
      for (int d = 0; d < 16; ++d) {
        const uint4 r = w[d];
        uh[d] = bf_lo(r.x)*x0 + bf_hi(r.x)*x1 + bf_lo(r.y)*x2 + bf_hi(r.y)*x3
              + bf_lo(r.z)*x4 + bf_hi(r.z)*x5 + bf_lo(r.w)*x6 + bf_hi(r.w)*x7;
      }
      float c;
      if (round == 0) {
        c = 0.1f;                     // softmax of zeros over 10 capsules
      } else {
        // cc[j,i] = u_hat . vsum[j]   (agreement is linear in v -> no cc storage)
        const float* vp = &vsh[bt * 160 + j * 16];
        float cc = 0.f;
        #pragma unroll
        for (int d = 0; d < 16; ++d) cc += uh[d] * vp[d];
        const int slot = (it << 2) + bt;
        ccx[slot][lane][j] = cc;
        __syncthreads();              // uniform: all 320 threads, every (it,bt)
        float m = ccx[slot][lane][0];
        #pragma unroll
        for (int jj = 1; jj < 10; ++jj) m = fmaxf(m, ccx[slot][lane][jj]);
        float den = 0.f;
        #pragma unroll
        for (int jj = 0; jj < 10; ++jj) den += __expf(ccx[slot][lane][jj] - m);
        c = __expf(cc - m) / den;
      }
      #pragma unroll
      for (int d = 0; d < 16; ++d) s_acc[bt][d] += c * uh[d];
    }
  }

  // width-32 butterfly reduce over the i-lanes
  #pragma unroll
  for (int bt = 0; bt < 4; ++bt)
    #pragma unroll
    for (int d = 0; d < 16; ++d) {
      float v = s_acc[bt][d];
      #pragma unroll
      for (int mk = 16; mk >= 1; mk >>= 1) v += __shfl_xor(v, mk, 32);
      s_acc[bt][d] = v;
    }

  if (lane == 0) {
    #pragma unroll
    for (int bt = 0; bt < 4; ++bt) {
      float* sp = s_glob + ((size_t)(b0 + bt) * J_N + j) * D_N;
      #pragma unroll
      for (int d = 0; d < 16; ++d)
        __hip_atomic_fetch_add(&sp[d], s_acc[bt][d],
                               __ATOMIC_RELAXED, __HIP_MEMORY_SCOPE_AGENT);
    }
  }
}

// squash s -> v; fold v into vsum (rounds 0,1) or emit fp32 output (round 2).
// Also re-zeroes s for the next round's atomics. grid 2560 = (b,j), 64 threads.
__global__ __launch_bounds__(64) void caps_squash(
    float* __restrict__ s_glob, float* __restrict__ vsum,
    float* __restrict__ out, const int round)
{
  const int bj = blockIdx.x;
  const int d  = threadIdx.x & 15;
  const float sv = s_glob[bj * 16 + d];
  float sq = sv * sv;
  sq += __shfl_xor(sq, 1, 16);
  sq += __shfl_xor(sq, 2, 16);
  sq += __shfl_xor(sq, 4, 16);
  sq += __shfl_xor(sq, 8, 16);
  const float coef = (sq / (1.f + sq)) * rsqrtf(sq + 1e-7f);
  const float v = coef * sv;
  if (threadIdx.x < 16) {
    s_glob[bj * 16 + d] = 0.f;
    if (round < 2) vsum[bj * 16 + d] += v;
    else           out[bj * 16 + d]  = v;
  }
}

extern "C" void kernel_launch(void* const* d_in, const int* in_sizes, int n_in,
                              void* d_out, int out_size, void* d_ws, size_t ws_size,
                              hipStream_t stream)
{
  const float* x = (const float*)d_in[0];   // inputs fp32 [256][1152][8]
  const float* W = (const float*)d_in[1];   // W fp32 [10][1152][16][8]

  // ws layout: [wbf: 737280 dw][s: 40960 f][vsum: 40960 f]  (~3.2 MB)
  unsigned int* wbf = (unsigned int*)d_ws;
  float* s    = (float*)(wbf + (size_t)J_N * IC_N * D_N * 4);
  float* vsum = s + (size_t)B_N * J_N * D_N;

  // ws is re-poisoned to 0xAA before every timed launch: prep re-converts W
  // and zeroes s/vsum every call (no memset -> no graph-capture risk).
  caps_prep<<<dim3(2880), dim3(256), 0, stream>>>(W, wbf, s);

  const dim3 pgrid(64, 9), pblk(320);
  for (int r = 0; r < 3; ++r) {
    caps_pass<<<pgrid, pblk, 0, stream>>>(x, wbf, s, vsum, r);
    caps_squash<<<dim3(B_N * J_N), dim3(64), 0, stream>>>(
        s, vsum, (float*)d_out, r);
  }
}

// Round 3
// 342.565 us; speedup vs baseline: 1.1289x; 1.1289x over previous
//
#include <hip/hip_runtime.h>
#include <hip/hip_bf16.h>

#define B_N   256
#define IC_N  1152
#define J_N   10
#define D_N   16

// packed bf16 pair (in a dword) -> fp32
__device__ __forceinline__ float bf_lo(unsigned int u){
  union { unsigned int i; float f; } c; c.i = u << 16; return c.f;
}
__device__ __forceinline__ float bf_hi(unsigned int u){
  union { unsigned int i; float f; } c; c.i = u & 0xffff0000u; return c.f;
}
// fp32 -> bf16 (round-to-nearest-even), in low 16 bits
__device__ __forceinline__ unsigned int rne_hi16(float f){
  union { float ff; unsigned int i; } c; c.ff = f;
  return (c.i + 0x7FFFu + ((c.i >> 16) & 1u)) >> 16;
}

// prep: build Wt4[j][d][i] = row d of W[j,i,:,:] as 8 packed bf16 (uint4),
// i-innermost so pass-kernel lane-i loads are fully coalesced (16 B/lane).
// Also zeroes the s/vsum scratch. One thread per (j,d,i) = 184320 threads.
__global__ __launch_bounds__(256) void caps_prep(
    const float* __restrict__ W, uint4* __restrict__ wt,
    float* __restrict__ zero_region)
{
  const int t = blockIdx.x * 256 + threadIdx.x;            // 0..184319
  if (t < 2 * B_N * J_N * D_N) zero_region[t] = 0.f;       // s + vsum
  const int j = t / (D_N * IC_N);
  const int r = t - j * (D_N * IC_N);
  const int d = r / IC_N;
  const int i = r - d * IC_N;
  const float4* src = (const float4*)(W + (((size_t)(j * IC_N + i) * D_N + d) << 3));
  const float4 a = src[0], b = src[1];
  uint4 q;
  q.x = rne_hi16(a.x) | (rne_hi16(a.y) << 16);
  q.y = rne_hi16(a.z) | (rne_hi16(a.w) << 16);
  q.z = rne_hi16(b.x) | (rne_hi16(b.y) << 16);
  q.w = rne_hi16(b.z) | (rne_hi16(b.w) << 16);
  wt[t] = q;   // t == (j*16 + d)*1152 + i  (write coalesced)
}

// Pass kernel: one routing round, u_hat regenerated in registers.
// grid (128 b-pairs, 18 i-chunks), block 320 = (j = tid/32) x (lane = i%32).
// W[j,i] (16 uint4, coalesced Wt4 loads) reused across bt=2 batches.
__global__ __launch_bounds__(320) void caps_pass(
    const float* __restrict__ x,          // inputs fp32 [B][IC][8]
    const uint4* __restrict__ wt,         // Wt4 [J][D][IC] packed bf16
    float* __restrict__ s_glob,           // [B][J][D] fp32 (atomic accum, pre-zeroed)
    const float* __restrict__ vsum,       // [B][J][D] running sum of v's
    const int round)
{
  __shared__ float ccx[4][32][11];    // softmax exchange, one slot per (it,bt)
  __shared__ float vsh[320];          // vsum staged for this block's 2 batches

  const int tid  = threadIdx.x;
  const int j    = tid >> 5;          // 0..9
  const int lane = tid & 31;
  const int b0   = blockIdx.x << 1;   // 2 batches per block
  const int chunk= blockIdx.y;        // 0..17, 64 i's each

  if (round > 0) {
    for (int q = tid; q < 320; q += 320)
      vsh[q] = vsum[b0 * (J_N * D_N) + q];
    __syncthreads();
  }

  float s_acc[2][16];
  #pragma unroll
  for (int bt = 0; bt < 2; ++bt)
    #pragma unroll
    for (int d = 0; d < 16; ++d) s_acc[bt][d] = 0.f;

  #pragma unroll
  for (int it = 0; it < 2; ++it) {
    const int i = chunk * 64 + it * 32 + lane;
    uint4 w[16];                      // W[j,i]: 16 rows (d) x 8 bf16 (e)
    #pragma unroll
    for (int d = 0; d < 16; ++d)
      w[d] = wt[(j * D_N + d) * IC_N + i];   // coalesced: lanes contiguous

    #pragma unroll
    for (int bt = 0; bt < 2; ++bt) {
      const int b = b0 + bt;
      const float4* xp = (const float4*)(x + ((size_t)(b * IC_N + i) << 3));
      const float4 xa = xp[0], xb = xp[1];
      const float x0 = xa.x, x1 = xa.y, x2 = xa.z, x3 = xa.w,
                  x4 = xb.x, x5 = xb.y, x6 = xb.z, x7 = xb.w;
      float uh[16];
      #pragma unroll
      for (int d = 0; d < 16; ++d) {
        const uint4 r = w[d];
        uh[d] = bf_lo(r.x)*x0 + bf_hi(r.x)*x1 + bf_lo(r.y)*x2 + bf_hi(r.y)*x3
              + bf_lo(r.z)*x4 + bf_hi(r.z)*x5 + bf_lo(r.w)*x6 + bf_hi(r.w)*x7;
      }
      float c;
      if (round == 0) {
        c = 0.1f;                     // softmax of zeros over 10 capsules
      } else {
        // cc[j,i] = u_hat . vsum[j]  (agreement linear in v -> no cc storage)
        const float* vp = &vsh[bt * 160 + j * 16];
        float cc = 0.f;
        #pragma unroll
        for (int d = 0; d < 16; ++d) cc += uh[d] * vp[d];
        const int slot = (it << 1) + bt;
        ccx[slot][lane][j] = cc;
        __syncthreads();              // uniform: all 320 threads, every (it,bt)
        float m = ccx[slot][lane][0];
        #pragma unroll
        for (int jj = 1; jj < 10; ++jj) m = fmaxf(m, ccx[slot][lane][jj]);
        float den = 0.f;
        #pragma unroll
        for (int jj = 0; jj < 10; ++jj) den += __expf(ccx[slot][lane][jj] - m);
        c = __expf(cc - m) / den;
      }
      #pragma unroll
      for (int d = 0; d < 16; ++d) s_acc[bt][d] += c * uh[d];
    }
  }

  // width-32 butterfly reduce over the i-lanes
  #pragma unroll
  for (int bt = 0; bt < 2; ++bt)
    #pragma unroll
    for (int d = 0; d < 16; ++d) {
      float v = s_acc[bt][d];
      #pragma unroll
      for (int mk = 16; mk >= 1; mk >>= 1) v += __shfl_xor(v, mk, 32);
      s_acc[bt][d] = v;
    }

  if (lane == 0) {
    #pragma unroll
    for (int bt = 0; bt < 2; ++bt) {
      float* sp = s_glob + ((size_t)(b0 + bt) * J_N + j) * D_N;
      #pragma unroll
      for (int d = 0; d < 16; ++d)
        __hip_atomic_fetch_add(&sp[d], s_acc[bt][d],
                               __ATOMIC_RELAXED, __HIP_MEMORY_SCOPE_AGENT);
    }
  }
}

// squash s -> v; fold v into vsum (rounds 0,1) or emit fp32 output (round 2).
// Also re-zeroes s for the next round's atomics. grid 2560 = (b,j), 64 threads.
__global__ __launch_bounds__(64) void caps_squash(
    float* __restrict__ s_glob, float* __restrict__ vsum,
    float* __restrict__ out, const int round)
{
  const int bj = blockIdx.x;
  const int d  = threadIdx.x & 15;
  const float sv = s_glob[bj * 16 + d];
  float sq = sv * sv;
  sq += __shfl_xor(sq, 1, 16);
  sq += __shfl_xor(sq, 2, 16);
  sq += __shfl_xor(sq, 4, 16);
  sq += __shfl_xor(sq, 8, 16);
  const float coef = (sq / (1.f + sq)) * rsqrtf(sq + 1e-7f);
  const float v = coef * sv;
  if (threadIdx.x < 16) {
    s_glob[bj * 16 + d] = 0.f;
    if (round < 2) vsum[bj * 16 + d] += v;
    else           out[bj * 16 + d]  = v;
  }
}

extern "C" void kernel_launch(void* const* d_in, const int* in_sizes, int n_in,
                              void* d_out, int out_size, void* d_ws, size_t ws_size,
                              hipStream_t stream)
{
  const float* x = (const float*)d_in[0];   // inputs fp32 [256][1152][8]
  const float* W = (const float*)d_in[1];   // W fp32 [10][1152][16][8]

  // ws layout: [Wt4: 184320 uint4][s: 40960 f][vsum: 40960 f]  (~3.3 MB)
  uint4* wt   = (uint4*)d_ws;
  float* s    = (float*)(wt + (size_t)J_N * D_N * IC_N);
  float* vsum = s + (size_t)B_N * J_N * D_N;

  // ws is re-poisoned to 0xAA before every timed launch: prep re-packs W
  // and zeroes s/vsum every call (no memset -> no graph-capture risk).
  caps_prep<<<dim3(720), dim3(256), 0, stream>>>(W, wt, s);

  const dim3 pgrid(128, 18), pblk(320);
  for (int r = 0; r < 3; ++r) {
    caps_pass<<<pgrid, pblk, 0, stream>>>(x, wt, s, vsum, r);
    caps_squash<<<dim3(B_N * J_N), dim3(64), 0, stream>>>(
        s, vsum, (float*)d_out, r);
  }
}

// Round 4
// 242.606 us; speedup vs baseline: 1.5941x; 1.4120x over previous
//
#include <hip/hip_runtime.h>

#define B_N   256
#define IC_N  1152
#define J_N   10
#define D_N   16

// packed bf16 pair (in a dword) -> fp32
__device__ __forceinline__ float bf_lo(unsigned int u){
  union { unsigned int i; float f; } c; c.i = u << 16; return c.f;
}
__device__ __forceinline__ float bf_hi(unsigned int u){
  union { unsigned int i; float f; } c; c.i = u & 0xffff0000u; return c.f;
}
// fp32 -> bf16 (round-to-nearest-even), in low 16 bits
__device__ __forceinline__ unsigned int rne_hi16(float f){
  union { float ff; unsigned int i; } c; c.ff = f;
  return (c.i + 0x7FFFu + ((c.i >> 16) & 1u)) >> 16;
}

// prep: Wt4[(j*16+d)][i] = row d of W[j,i,:,:] as 8 packed bf16 (uint4),
// i-innermost so pass-kernel lane-i loads are coalesced. Zeroes s/vsum.
__global__ __launch_bounds__(256) void caps_prep(
    const float* __restrict__ W, uint4* __restrict__ wt,
    float* __restrict__ zero_region)
{
  const int t = blockIdx.x * 256 + threadIdx.x;            // 0..184319
  if (t < 2 * B_N * J_N * D_N) zero_region[t] = 0.f;       // s + vsum
  const int j = t / (D_N * IC_N);
  const int r = t - j * (D_N * IC_N);
  const int d = r / IC_N;
  const int i = r - d * IC_N;
  const float4* src = (const float4*)(W + (((size_t)(j * IC_N + i) * D_N + d) << 3));
  const float4 a = src[0], b = src[1];
  uint4 q;
  q.x = rne_hi16(a.x) | (rne_hi16(a.y) << 16);
  q.y = rne_hi16(a.z) | (rne_hi16(a.w) << 16);
  q.z = rne_hi16(b.x) | (rne_hi16(b.y) << 16);
  q.w = rne_hi16(b.z) | (rne_hi16(b.w) << 16);
  wt[t] = q;
}

// Pass kernel. block 640 = (j 0..9) x (d-half 0..1) x (lane=i 0..31).
// grid (128 b-pairs, 18 i-chunks of 64). W streamed one uint4 at a time
// (no w[16] array -> no spill); uh kept only as [it 2][bt 2][8] halves.
__global__ __launch_bounds__(640, 4) void caps_pass(
    const float* __restrict__ x,          // inputs fp32 [B][IC][8]
    const uint4* __restrict__ wt,         // Wt4 [(J*16+d)][IC] packed bf16
    float* __restrict__ s_glob,           // [B][J][D] fp32 atomic accum (zeroed)
    const float* __restrict__ vsum,       // [B][J][D] running sum of v's
    const int round)
{
  __shared__ float vsh[320];            // vsum for the 2 batches
  __shared__ float ccx[4][32][21];      // cc halves per (it,bt) slot; pad 21 (gcd 32 =1)
  __shared__ float csx[4][32][2];       // (m, 1/den) per slot

  const int tid  = threadIdx.x;
  const int lane = tid & 31;
  const int grp  = tid >> 5;            // 0..19 (wave64 = same j, both halves)
  const int j    = grp >> 1;
  const int h    = grp & 1;
  const int b0   = blockIdx.x << 1;
  const int chunk= blockIdx.y;          // 0..17

  if (round > 0) {
    if (tid < 320) vsh[tid] = vsum[b0 * (J_N * D_N) + tid];
    __syncthreads();
  }

  float uh[2][2][8];                    // [it][bt][d-in-half]
  float s_acc[2][8];
  #pragma unroll
  for (int bt = 0; bt < 2; ++bt)
    #pragma unroll
    for (int d = 0; d < 8; ++d) s_acc[bt][d] = 0.f;

  const int wbase = (j * D_N + h * 8) * IC_N;

  #pragma unroll
  for (int it = 0; it < 2; ++it) {
    const int i = chunk * 64 + it * 32 + lane;
    float xr[2][8];
    #pragma unroll
    for (int bt = 0; bt < 2; ++bt) {
      const float4* xp = (const float4*)(x + ((size_t)((b0 + bt) * IC_N + i) << 3));
      const float4 xa = xp[0], xb = xp[1];
      xr[bt][0]=xa.x; xr[bt][1]=xa.y; xr[bt][2]=xa.z; xr[bt][3]=xa.w;
      xr[bt][4]=xb.x; xr[bt][5]=xb.y; xr[bt][6]=xb.z; xr[bt][7]=xb.w;
    }
    float ccp[2] = {0.f, 0.f};
    const uint4* wp = wt + wbase + i;
    #pragma unroll
    for (int d = 0; d < 8; ++d) {
      const uint4 w = wp[d * IC_N];     // coalesced: 32 lanes x 16 B contiguous
      const float f0=bf_lo(w.x), f1=bf_hi(w.x), f2=bf_lo(w.y), f3=bf_hi(w.y),
                  f4=bf_lo(w.z), f5=bf_hi(w.z), f6=bf_lo(w.w), f7=bf_hi(w.w);
      #pragma unroll
      for (int bt = 0; bt < 2; ++bt) {
        const float u = f0*xr[bt][0]+f1*xr[bt][1]+f2*xr[bt][2]+f3*xr[bt][3]
                       +f4*xr[bt][4]+f5*xr[bt][5]+f6*xr[bt][6]+f7*xr[bt][7];
        uh[it][bt][d] = u;
        if (round > 0) ccp[bt] += u * vsh[bt * 160 + j * 16 + h * 8 + d];
      }
    }
    if (round > 0) {
      ccx[it * 2 + 0][lane][j * 2 + h] = ccp[0];
      ccx[it * 2 + 1][lane][j * 2 + h] = ccp[1];
    }
  }

  if (round > 0) {
    __syncthreads();
    if (tid < 128) {                    // one thread per (slot, i-lane): softmax once
      const int slot = tid >> 5, ln = tid & 31;
      float cc[10];
      #pragma unroll
      for (int jj = 0; jj < 10; ++jj)
        cc[jj] = ccx[slot][ln][2*jj] + ccx[slot][ln][2*jj + 1];
      float m = cc[0];
      #pragma unroll
      for (int jj = 1; jj < 10; ++jj) m = fmaxf(m, cc[jj]);
      float den = 0.f;
      #pragma unroll
      for (int jj = 0; jj < 10; ++jj) den += __expf(cc[jj] - m);
      csx[slot][ln][0] = m;
      csx[slot][ln][1] = __builtin_amdgcn_rcpf(den);
    }
    __syncthreads();
    #pragma unroll
    for (int it = 0; it < 2; ++it)
      #pragma unroll
      for (int bt = 0; bt < 2; ++bt) {
        const int slot = it * 2 + bt;
        const float own = ccx[slot][lane][2*j] + ccx[slot][lane][2*j + 1];
        const float c = __expf(own - csx[slot][lane][0]) * csx[slot][lane][1];
        #pragma unroll
        for (int d = 0; d < 8; ++d) s_acc[bt][d] += c * uh[it][bt][d];
      }
  } else {
    #pragma unroll
    for (int it = 0; it < 2; ++it)
      #pragma unroll
      for (int bt = 0; bt < 2; ++bt)
        #pragma unroll
        for (int d = 0; d < 8; ++d) s_acc[bt][d] += uh[it][bt][d];
    #pragma unroll
    for (int bt = 0; bt < 2; ++bt)
      #pragma unroll
      for (int d = 0; d < 8; ++d) s_acc[bt][d] *= 0.1f;   // softmax(0) over 10 j
  }

  // butterfly reduce over the 32 i-lanes
  #pragma unroll
  for (int bt = 0; bt < 2; ++bt)
    #pragma unroll
    for (int d = 0; d < 8; ++d) {
      float v = s_acc[bt][d];
      #pragma unroll
      for (int mk = 16; mk >= 1; mk >>= 1) v += __shfl_xor(v, mk, 32);
      s_acc[bt][d] = v;
    }

  if (lane == 0) {
    #pragma unroll
    for (int bt = 0; bt < 2; ++bt) {
      float* sp = s_glob + ((size_t)(b0 + bt) * J_N + j) * D_N + h * 8;
      #pragma unroll
      for (int d = 0; d < 8; ++d)
        __hip_atomic_fetch_add(&sp[d], s_acc[bt][d],
                               __ATOMIC_RELAXED, __HIP_MEMORY_SCOPE_AGENT);
    }
  }
}

// squash s -> v; fold v into vsum (rounds 0,1) or emit fp32 output (round 2).
// Also re-zeroes s for the next round's atomics.
__global__ __launch_bounds__(64) void caps_squash(
    float* __restrict__ s_glob, float* __restrict__ vsum,
    float* __restrict__ out, const int round)
{
  const int bj = blockIdx.x;
  const int d  = threadIdx.x & 15;
  const float sv = s_glob[bj * 16 + d];
  float sq = sv * sv;
  sq += __shfl_xor(sq, 1, 16);
  sq += __shfl_xor(sq, 2, 16);
  sq += __shfl_xor(sq, 4, 16);
  sq += __shfl_xor(sq, 8, 16);
  const float coef = (sq / (1.f + sq)) * rsqrtf(sq + 1e-7f);
  const float v = coef * sv;
  if (threadIdx.x < 16) {
    s_glob[bj * 16 + d] = 0.f;
    if (round < 2) vsum[bj * 16 + d] += v;
    else           out[bj * 16 + d]  = v;
  }
}

extern "C" void kernel_launch(void* const* d_in, const int* in_sizes, int n_in,
                              void* d_out, int out_size, void* d_ws, size_t ws_size,
                              hipStream_t stream)
{
  const float* x = (const float*)d_in[0];   // inputs fp32 [256][1152][8]
  const float* W = (const float*)d_in[1];   // W fp32 [10][1152][16][8]

  // ws layout: [Wt4: 184320 uint4][s: 40960 f][vsum: 40960 f]  (~3.3 MB)
  uint4* wt   = (uint4*)d_ws;
  float* s    = (float*)(wt + (size_t)J_N * D_N * IC_N);
  float* vsum = s + (size_t)B_N * J_N * D_N;

  // prep re-packs W and zeroes s/vsum every call (ws is re-poisoned to 0xAA).
  caps_prep<<<dim3(720), dim3(256), 0, stream>>>(W, wt, s);

  const dim3 pgrid(128, 18), pblk(640);
  for (int r = 0; r < 3; ++r) {
    caps_pass<<<pgrid, pblk, 0, stream>>>(x, wt, s, vsum, r);
    caps_squash<<<dim3(B_N * J_N), dim3(64), 0, stream>>>(
        s, vsum, (float*)d_out, r);
  }
}

// Round 5
// 178.892 us; speedup vs baseline: 2.1618x; 1.3562x over previous
//
#include <hip/hip_runtime.h>

#define B_N 256
#define IC_N 1152
#define J_N 10
#define D_N 16

typedef __attribute__((ext_vector_type(8))) short short8;
typedef __attribute__((ext_vector_type(4))) float floatx4;

__device__ __forceinline__ float bfu_to_f(unsigned short u){
  union { unsigned int i; float f; } c; c.i = ((unsigned int)u) << 16; return c.f;
}
__device__ __forceinline__ float bf_lo(unsigned int u){
  union { unsigned int i; float f; } c; c.i = u << 16; return c.f;
}
__device__ __forceinline__ float bf_hi(unsigned int u){
  union { unsigned int i; float f; } c; c.i = u & 0xffff0000u; return c.f;
}
__device__ __forceinline__ unsigned int rne16(float f){
  union { float ff; unsigned int i; } c; c.ff = f;
  return (c.i + 0x7FFFu + ((c.i >> 16) & 1u)) >> 16;
}
__device__ __forceinline__ unsigned int pack_rne(float lo, float hi){
  return rne16(lo) | (rne16(hi) << 16);
}
// trunc-to-bf16 pack in 1 op (v_perm): bytes {hi[3],hi[2],lo[3],lo[2]}
__device__ __forceinline__ unsigned int pack_trunc(float lo, float hi){
  union { float f; unsigned int u; } a, b; a.f = lo; b.f = hi;
  return __builtin_amdgcn_perm(b.u, a.u, 0x07060302u);
}

// prep: swizzle W (fp32) into the two MFMA B-fragment layouts (bf16) + zero vsum.
// Ws  [j][kt=i>>2][lane=( i&3)*16+d][e]   for s-GEMM  B[k=(i%4)*8+e][n=d]
// Wcc [j][ip=i>>1][lane=(d>>3)*16+(i&1)*8+e][idx=d&7] for cc-GEMM B[k=d][n=(i&1,e)]
__global__ __launch_bounds__(256) void caps_prep(
    const float* __restrict__ W, uint4* __restrict__ wsf,
    uint4* __restrict__ wccf, float* __restrict__ vsum)
{
  const int t = blockIdx.x * 256 + threadIdx.x;          // 0..368639
  if (t < B_N * J_N * D_N) vsum[t] = 0.f;
  if (t < 184320) {            // Ws: t = (j*1152 + i)*16 + d
    const int d  = t & 15;
    const int ji = t >> 4;
    const int i  = ji % IC_N;
    const int j  = ji / IC_N;
    const float4* src = (const float4*)(W + ((size_t)t << 3));
    const float4 a = src[0], b = src[1];
    uint4 q;
    q.x = pack_rne(a.x, a.y); q.y = pack_rne(a.z, a.w);
    q.z = pack_rne(b.x, b.y); q.w = pack_rne(b.z, b.w);
    wsf[(j * 288 + (i >> 2)) * 64 + (i & 3) * 16 + d] = q;
  } else {                     // Wcc: t2 = (j*576 + ip)*32 + lane
    const int t2   = t - 184320;
    const int lane = t2 & 31;
    const int jip  = t2 >> 5;
    const int ip   = jip % 576;
    const int j    = jip / 576;
    const int i    = ip * 2 + ((lane & 15) >> 3);
    const int e    = lane & 7;
    const int d0   = (lane >> 4) * 8;
    const float* src = W + (((size_t)(j * IC_N + i) * D_N + d0) << 3) + e;
    uint4 q;
    q.x = pack_rne(src[0],  src[8]);  q.y = pack_rne(src[16], src[24]);
    q.z = pack_rne(src[32], src[40]); q.w = pack_rne(src[48], src[56]);
    wccf[t2] = q;
  }
}

// Pass: block = (btile of 16 b, ichunk of 64 i), 640 thr = 10 waves, wave = j.
// cc via MFMA(vsum, Wcc) fused-epilogue; softmax in LDS; s via MFMA(c*x, Ws).
__global__ __launch_bounds__(640, 5) void caps_pass(
    const float* __restrict__ x,          // fp32 [256][1152][8]
    const uint4* __restrict__ wsf,
    const uint4* __restrict__ wccf,
    const float* __restrict__ vsum,       // fp32 [256][10][16]
    float* __restrict__ s_part,           // [16][18][10][16][16]
    const int round)
{
  __shared__ unsigned short xA[64 * 16 * 8];   // [i][b][e] bf16, 16 KB
  __shared__ unsigned short vsA[10 * 16 * 16]; // [j][b][d] bf16,  5 KB
  __shared__ float ccl[64 * 10 * 16];          // [i][j][b] fp32, 40 KB

  const int tid  = threadIdx.x;
  const int wave = tid >> 6;          // = j
  const int lane = tid & 63;
  const int quad = lane >> 4;         // 0..3
  const int col  = lane & 15;
  const int btile = blockIdx.x;       // 0..15
  const int chunk = blockIdx.y;       // 0..17
  const int b0    = btile << 4;
  const int ibase = chunk << 6;

  // stage x tile -> bf16 A-layout [i][b][e]
  for (int p = tid; p < 1024; p += 640) {
    const int i = p >> 4, b = p & 15;
    const float4* xp = (const float4*)(x + ((size_t)((b0 + b) * IC_N + ibase + i) << 3));
    const float4 a = xp[0], c = xp[1];
    uint4 q;
    q.x = pack_rne(a.x, a.y); q.y = pack_rne(a.z, a.w);
    q.z = pack_rne(c.x, c.y); q.w = pack_rne(c.z, c.w);
    ((uint4*)xA)[p] = q;
  }
  if (round > 0) {                    // stage vsum tile -> bf16 [j][b][d]
    const int q4 = tid * 4;           // 640*4 = 2560 exactly
    const int j = q4 >> 8, rem = q4 & 255, b = rem >> 4, dd = rem & 15;
    const float4 vs = *(const float4*)(vsum + (((size_t)(b0 + b) * J_N + j) << 4) + dd);
    unsigned int lo = pack_rne(vs.x, vs.y), hi = pack_rne(vs.z, vs.w);
    *(unsigned int*)(vsA + q4)     = lo;
    *(unsigned int*)(vsA + q4 + 2) = hi;
  }
  __syncthreads();

  if (round > 0) {
    // A-frag: vsum[b=col][d = quad*8+idx], quads 2,3 are K-padding zeros
    short8 av = {0,0,0,0,0,0,0,0};
    if (quad < 2) av = *(const short8*)(vsA + ((wave * 16 + col) << 4) + quad * 8);

    for (int ipl = 0; ipl < 32; ++ipl) {
      short8 bv = {0,0,0,0,0,0,0,0};
      if (lane < 32)
        bv = *(const short8*)(wccf + (size_t)(wave * 576 + (chunk << 5) + ipl) * 32 + lane);
      floatx4 tf = {0.f, 0.f, 0.f, 0.f};
      tf = __builtin_amdgcn_mfma_f32_16x16x32_bf16(av, bv, tf, 0, 0, 0);
      // epilogue: T[b][(i,e)] * x[b,i,e], reduce over e (cols 0-7 / 8-15)
      const int il = ipl * 2 + (col >> 3);
      const int e  = col & 7;
      float prod[4];
      #pragma unroll
      for (int r = 0; r < 4; ++r)
        prod[r] = tf[r] * bfu_to_f(xA[((il << 4) + quad * 4 + r) * 8 + e]);
      #pragma unroll
      for (int mk = 1; mk <= 4; mk <<= 1)
        #pragma unroll
        for (int r = 0; r < 4; ++r) prod[r] += __shfl_xor(prod[r], mk, 64);
      if ((lane & 7) == 0) {          // cols 0,8 hold cc[i][b-quad]
        floatx4 w4 = {prod[0], prod[1], prod[2], prod[3]};
        *(floatx4*)(ccl + (il * 10 + wave) * 16 + quad * 4) = w4;
      }
    }
    __syncthreads();
    // softmax over j, in place (c replaces cc)
    for (int p = tid; p < 1024; p += 640) {
      const int i = p >> 4, b = p & 15;
      float* base = ccl + i * 160 + b;
      float cc[10];
      #pragma unroll
      for (int j = 0; j < 10; ++j) cc[j] = base[j * 16];
      float m = cc[0];
      #pragma unroll
      for (int j = 1; j < 10; ++j) m = fmaxf(m, cc[j]);
      float den = 0.f;
      #pragma unroll
      for (int j = 0; j < 10; ++j) { cc[j] = __expf(cc[j] - m); den += cc[j]; }
      const float rd = __builtin_amdgcn_rcpf(den);
      #pragma unroll
      for (int j = 0; j < 10; ++j) base[j * 16] = cc[j] * rd;
    }
    __syncthreads();
  }

  // s-GEMM: acc[b][d] += A'(c*x) @ Ws over K = 512 (16 k-tiles of 32)
  floatx4 acc = {0.f, 0.f, 0.f, 0.f};
  #pragma unroll 4
  for (int kt = 0; kt < 16; ++kt) {
    const short8 bfrag = *(const short8*)(wsf + (size_t)(wave * 288 + (chunk << 4) + kt) * 64 + lane);
    const int il = kt * 4 + quad;     // lane's i for this k-tile (8 e's)
    const uint4 xv = ((const uint4*)xA)[(il << 4) + col];
    const float c = (round > 0) ? ccl[(il * 10 + wave) * 16 + col] : 0.1f;
    short8 af;
    unsigned int* aq = (unsigned int*)&af;
    aq[0] = pack_trunc(bf_lo(xv.x) * c, bf_hi(xv.x) * c);
    aq[1] = pack_trunc(bf_lo(xv.y) * c, bf_hi(xv.y) * c);
    aq[2] = pack_trunc(bf_lo(xv.z) * c, bf_hi(xv.z) * c);
    aq[3] = pack_trunc(bf_lo(xv.w) * c, bf_hi(xv.w) * c);
    acc = __builtin_amdgcn_mfma_f32_16x16x32_bf16(af, bfrag, acc, 0, 0, 0);
  }
  // store partial: s_part[btile][chunk][j][b=quad*4+r][d=col]
  float* sp = s_part + ((((size_t)btile * 18 + chunk) * 10 + wave) * 16 + quad * 4) * 16 + col;
  #pragma unroll
  for (int r = 0; r < 4; ++r) sp[r * 16] = acc[r];
}

// squash: reduce 18 chunk-partials, squash, update vsum / emit output.
__global__ __launch_bounds__(256) void caps_squash(
    const float* __restrict__ s_part, float* __restrict__ vsum,
    float* __restrict__ out, const int round)
{
  const int t  = blockIdx.x * 256 + threadIdx.x;   // 40960 = 2560 (b,j) x 16 d
  const int d  = t & 15;
  const int bj = t >> 4;
  const int b  = bj / 10, j = bj % 10;
  const int btile = b >> 4, brem = b & 15;
  float s = 0.f;
  for (int ch = 0; ch < 18; ++ch)
    s += s_part[((((size_t)btile * 18 + ch) * 10 + j) * 16 + brem) * 16 + d];
  float sq = s * s;
  sq += __shfl_xor(sq, 1, 16);
  sq += __shfl_xor(sq, 2, 16);
  sq += __shfl_xor(sq, 4, 16);
  sq += __shfl_xor(sq, 8, 16);
  const float coef = (sq / (1.f + sq)) * rsqrtf(sq + 1e-7f);
  const float v = coef * s;
  if (round < 2) vsum[bj * 16 + d] += v;
  else           out[bj * 16 + d]  = v;
}

extern "C" void kernel_launch(void* const* d_in, const int* in_sizes, int n_in,
                              void* d_out, int out_size, void* d_ws, size_t ws_size,
                              hipStream_t stream)
{
  const float* x = (const float*)d_in[0];   // [256][1152][8] fp32
  const float* W = (const float*)d_in[1];   // [10][1152][16][8] fp32

  // ws: Ws 2.95 MB | Wcc 2.95 MB | s_part 2.95 MB | vsum 160 KB  (~9 MB)
  uint4* wsf   = (uint4*)d_ws;                            // 184320 uint4
  uint4* wccf  = wsf + 184320;                            // 184320 uint4
  float* s_prt = (float*)(wccf + 184320);                 // 737280 f
  float* vsum  = s_prt + 737280;                          // 40960 f

  caps_prep<<<dim3(1440), dim3(256), 0, stream>>>(W, wsf, wccf, vsum);

  for (int r = 0; r < 3; ++r) {
    caps_pass<<<dim3(16, 18), dim3(640), 0, stream>>>(x, wsf, wccf, vsum, s_prt, r);
    caps_squash<<<dim3(160), dim3(256), 0, stream>>>(s_prt, vsum, (float*)d_out, r);
  }
}

// Round 6
// 147.469 us; speedup vs baseline: 2.6225x; 1.2131x over previous
//
#include <hip/hip_runtime.h>

#define B_N 256
#define IC_N 1152
#define J_N 10
#define D_N 16

typedef __attribute__((ext_vector_type(8))) short short8;
typedef __attribute__((ext_vector_type(4))) float floatx4;

__device__ __forceinline__ float bf_lo(unsigned int u){
  union { unsigned int i; float f; } c; c.i = u << 16; return c.f;
}
__device__ __forceinline__ float bf_hi(unsigned int u){
  union { unsigned int i; float f; } c; c.i = u & 0xffff0000u; return c.f;
}
__device__ __forceinline__ unsigned int rne16(float f){
  union { float ff; unsigned int i; } c; c.ff = f;
  return (c.i + 0x7FFFu + ((c.i >> 16) & 1u)) >> 16;
}
__device__ __forceinline__ unsigned int pack_rne(float lo, float hi){
  return rne16(lo) | (rne16(hi) << 16);
}
// trunc-to-bf16 pack in 1 op (v_perm)
__device__ __forceinline__ unsigned int pack_trunc(float lo, float hi){
  union { float f; unsigned int u; } a, b; a.f = lo; b.f = hi;
  return __builtin_amdgcn_perm(b.u, a.u, 0x07060302u);
}

// prep (one dispatch, 3 segments):
//  [0,184320):    Ws B-frags  (k=(i%4)*8+e, n=d; layout verified in R5) + zero vsum
//  [184320,368640): Wcc2 B-frags for the per-e cc MFMAs: B_e[k=d][n=i16],
//                  compact (k<16 -> lanes 0..31 only)
//  [368640,663552): xbf[i][b] = x[b][i][e0..7] packed bf16 uint4 (transposed)
__global__ __launch_bounds__(256) void caps_prep(
    const float* __restrict__ W, const float* __restrict__ x,
    uint4* __restrict__ wsf, uint4* __restrict__ wcc2,
    uint4* __restrict__ xbf, float* __restrict__ vsum)
{
  const int t = blockIdx.x * 256 + threadIdx.x;   // 0..663551
  if (t < 184320) {
    if (t < B_N * J_N * D_N) vsum[t] = 0.f;
    const int d  = t & 15;
    const int ji = t >> 4;
    const int i  = ji % IC_N;
    const int j  = ji / IC_N;
    const float4* src = (const float4*)(W + ((size_t)t << 3));
    const float4 a = src[0], b = src[1];
    uint4 q;
    q.x = pack_rne(a.x, a.y); q.y = pack_rne(a.z, a.w);
    q.z = pack_rne(b.x, b.y); q.w = pack_rne(b.z, b.w);
    wsf[(j * 288 + (i >> 2)) * 64 + (i & 3) * 16 + d] = q;
  } else if (t < 368640) {
    const int t2    = t - 184320;
    const int lane  = t2 & 31;
    const int rest  = t2 >> 5;
    const int itile = rest % 72;
    const int je    = rest / 72;        // 0..79
    const int e     = je & 7;
    const int j     = je >> 3;
    const int i     = itile * 16 + (lane & 15);
    const int dbase = (lane >> 4) * 8;
    const float* src = W + (((size_t)(j * IC_N + i) * D_N + dbase) << 3) + e;
    uint4 q;
    q.x = pack_rne(src[0],  src[8]);  q.y = pack_rne(src[16], src[24]);
    q.z = pack_rne(src[32], src[40]); q.w = pack_rne(src[48], src[56]);
    wcc2[t2] = q;
  } else {
    const int t3 = t - 368640;          // = b*1152 + i
    const int i  = t3 % IC_N;
    const int b  = t3 / IC_N;
    const float4* src = (const float4*)(x + ((size_t)t3 << 3));
    const float4 a = src[0], c = src[1];
    uint4 q;
    q.x = pack_rne(a.x, a.y); q.y = pack_rne(a.z, a.w);
    q.z = pack_rne(c.x, c.y); q.w = pack_rne(c.z, c.w);
    xbf[(size_t)i * 256 + b] = q;
  }
}

// Pass: grid (btile 16, chunk 36 of 32 i), block 640 = 10 waves, wave = j.
// Phase A (round>0): cc[b,i] via 8 per-e MFMAs accumulated in C-layout regs
// (no shuffles, no x LDS); softmax in ccl (b-dim padded to 17).
// Phase B: s-GEMM, A-frags built from coalesced global xbf + c from ccl.
__global__ __launch_bounds__(640) void caps_pass(
    const uint4* __restrict__ xbf,
    const uint4* __restrict__ wsf,
    const uint4* __restrict__ wcc2,
    const uint4* __restrict__ vsbf,     // vsum bf16, [(b*10+j)*8 + d/2] uints
    float* __restrict__ s_part,         // [16][36][10][16][16]
    const int round)
{
  __shared__ float ccl[10 * 32 * 17];   // [j][i_local][b pad 17], 21.76 KB

  const int tid  = threadIdx.x;
  const int wave = tid >> 6;            // = j
  const int lane = tid & 63;
  const int quad = lane >> 4;
  const int col  = lane & 15;
  const int b0   = blockIdx.x << 4;
  const int i0   = blockIdx.y << 5;     // 32 i per chunk

  if (round > 0) {
    // A-frag: vsum[b=col][d=quad*8+idx]; quads 2,3 are K-pad zeros
    short8 av = {0,0,0,0,0,0,0,0};
    if (quad < 2)
      av = *(const short8*)&vsbf[((size_t)(b0 + col) * J_N + wave) * 2 + quad];

    #pragma unroll
    for (int t2 = 0; t2 < 2; ++t2) {    // two 16-i tiles
      uint4 xr[4];                      // x[b=quad*4+r][i=col][e0..7]
      #pragma unroll
      for (int r = 0; r < 4; ++r)
        xr[r] = xbf[(size_t)(i0 + t2 * 16 + col) * 256 + b0 + quad * 4 + r];
      floatx4 cc4 = {0.f, 0.f, 0.f, 0.f};
      #pragma unroll
      for (int e = 0; e < 8; ++e) {
        short8 bv = {0,0,0,0,0,0,0,0};  // k>=16 zeros live in lanes 32..63
        if (lane < 32)
          bv = *(const short8*)&wcc2[(((size_t)wave * 8 + e) * 72
                                      + blockIdx.y * 2 + t2) * 32 + lane];
        floatx4 tf = {0.f, 0.f, 0.f, 0.f};
        tf = __builtin_amdgcn_mfma_f32_16x16x32_bf16(av, bv, tf, 0, 0, 0);
        #pragma unroll
        for (int r = 0; r < 4; ++r) {
          const unsigned int u = ((const unsigned int*)&xr[r])[e >> 1];
          const float xe = (e & 1) ? bf_hi(u) : bf_lo(u);
          cc4[r] += tf[r] * xe;
        }
      }
      #pragma unroll
      for (int r = 0; r < 4; ++r)
        ccl[(wave * 32 + t2 * 16 + col) * 17 + quad * 4 + r] = cc4[r];
    }
    __syncthreads();
    // softmax over j for each (i,b); c written back in place
    if (tid < 512) {
      const int i = tid >> 4, b = tid & 15;
      float cc[10];
      #pragma unroll
      for (int j = 0; j < 10; ++j) cc[j] = ccl[(j * 32 + i) * 17 + b];
      float m = cc[0];
      #pragma unroll
      for (int j = 1; j < 10; ++j) m = fmaxf(m, cc[j]);
      float den = 0.f;
      #pragma unroll
      for (int j = 0; j < 10; ++j) { cc[j] = __expf(cc[j] - m); den += cc[j]; }
      const float rd = __builtin_amdgcn_rcpf(den);
      #pragma unroll
      for (int j = 0; j < 10; ++j) ccl[(j * 32 + i) * 17 + b] = cc[j] * rd;
    }
    __syncthreads();
  }

  // Phase B: s[b,d] = sum_k (c*x)[b,k] Ws[k,d], K = 256 (8 k-tiles)
  floatx4 acc = {0.f, 0.f, 0.f, 0.f};
  #pragma unroll
  for (int kt = 0; kt < 8; ++kt) {
    const int il = kt * 4 + quad;       // lane's i within chunk
    const uint4 xq = xbf[(size_t)(i0 + il) * 256 + b0 + col];
    const float c = (round > 0) ? ccl[(wave * 32 + il) * 17 + col] : 0.1f;
    short8 af;
    unsigned int* aq = (unsigned int*)&af;
    aq[0] = pack_trunc(bf_lo(xq.x) * c, bf_hi(xq.x) * c);
    aq[1] = pack_trunc(bf_lo(xq.y) * c, bf_hi(xq.y) * c);
    aq[2] = pack_trunc(bf_lo(xq.z) * c, bf_hi(xq.z) * c);
    aq[3] = pack_trunc(bf_lo(xq.w) * c, bf_hi(xq.w) * c);
    const short8 bfrag = *(const short8*)&wsf[((size_t)wave * 288
                                               + blockIdx.y * 8 + kt) * 64 + lane];
    acc = __builtin_amdgcn_mfma_f32_16x16x32_bf16(af, bfrag, acc, 0, 0, 0);
  }
  float* sp = s_part + ((((size_t)blockIdx.x * 36 + blockIdx.y) * 10 + wave) * 16
                        + quad * 4) * 16 + col;
  #pragma unroll
  for (int r = 0; r < 4; ++r) sp[r * 16] = acc[r];
}

// squash: reduce 36 chunk-partials, squash; update vsum (fp32) + vsbf (bf16
// A-frag source) on rounds 0,1; emit output on round 2.
__global__ __launch_bounds__(256) void caps_squash(
    const float* __restrict__ s_part, float* __restrict__ vsum,
    uint4* __restrict__ vsbf, float* __restrict__ out, const int round)
{
  __shared__ float vloc[256];
  const int t  = blockIdx.x * 256 + threadIdx.x;  // 40960
  const int d  = t & 15;
  const int bj = t >> 4;                          // = b*10 + j
  const int b  = bj / 10, j = bj - b * 10;
  const int btile = b >> 4, brem = b & 15;
  float s = 0.f;
  for (int ch = 0; ch < 36; ++ch)
    s += s_part[(((size_t)btile * 36 + ch) * 10 + j) * 256 + brem * 16 + d];
  float sq = s * s;
  sq += __shfl_xor(sq, 1, 16);
  sq += __shfl_xor(sq, 2, 16);
  sq += __shfl_xor(sq, 4, 16);
  sq += __shfl_xor(sq, 8, 16);
  const float coef = (sq / (1.f + sq)) * rsqrtf(sq + 1e-7f);
  const float v = coef * s;
  if (round < 2) {
    const float vt = vsum[t] + v;
    vsum[t] = vt;
    vloc[threadIdx.x] = vt;
    __syncthreads();
    if (threadIdx.x < 128) {
      const int p = threadIdx.x;
      const int bjl = p >> 3, dp = p & 7;
      const unsigned int u = pack_rne(vloc[bjl * 16 + dp * 2],
                                      vloc[bjl * 16 + dp * 2 + 1]);
      ((unsigned int*)vsbf)[((size_t)blockIdx.x * 16 + bjl) * 8 + dp] = u;
    }
  } else {
    out[t] = v;
  }
}

extern "C" void kernel_launch(void* const* d_in, const int* in_sizes, int n_in,
                              void* d_out, int out_size, void* d_ws, size_t ws_size,
                              hipStream_t stream)
{
  const float* x = (const float*)d_in[0];   // [256][1152][8] fp32
  const float* W = (const float*)d_in[1];   // [10][1152][16][8] fp32

  // ws: Ws 2.95M | Wcc2 2.95M | xbf 4.72M | s_part 5.90M | vsum 164K | vsbf 82K
  uint4* wsf   = (uint4*)d_ws;                        // 184320 uint4
  uint4* wcc2  = wsf + 184320;                        // 184320 uint4
  uint4* xbf   = wcc2 + 184320;                       // 294912 uint4
  float* s_prt = (float*)(xbf + 294912);              // 1474560 f
  float* vsum  = s_prt + 1474560;                     // 40960 f
  uint4* vsbf  = (uint4*)(vsum + 40960);              // 5120 uint4

  caps_prep<<<dim3(2592), dim3(256), 0, stream>>>(W, x, wsf, wcc2, xbf, vsum);

  for (int r = 0; r < 3; ++r) {
    caps_pass<<<dim3(16, 36), dim3(640), 0, stream>>>(
        xbf, wsf, wcc2, vsbf, s_prt, r);
    caps_squash<<<dim3(160), dim3(256), 0, stream>>>(
        s_prt, vsum, vsbf, (float*)d_out, r);
  }
}

// Round 8
// 131.045 us; speedup vs baseline: 2.9511x; 1.1253x over previous
//
#include <hip/hip_runtime.h>

#define B_N 256
#define IC_N 1152
#define J_N 10
#define D_N 16

typedef __attribute__((ext_vector_type(8))) short short8;
typedef __attribute__((ext_vector_type(4))) float floatx4;

union u4s8 { uint4 u; short8 s; };

__device__ __forceinline__ float bf_lo(unsigned int u){
  union { unsigned int i; float f; } c; c.i = u << 16; return c.f;
}
__device__ __forceinline__ float bf_hi(unsigned int u){
  union { unsigned int i; float f; } c; c.i = u & 0xffff0000u; return c.f;
}
__device__ __forceinline__ unsigned int rne16(float f){
  union { float ff; unsigned int i; } c; c.ff = f;
  return (c.i + 0x7FFFu + ((c.i >> 16) & 1u)) >> 16;
}
__device__ __forceinline__ unsigned int pack_rne(float lo, float hi){
  return rne16(lo) | (rne16(hi) << 16);
}
// trunc-to-bf16 pack in 1 op (v_perm)
__device__ __forceinline__ unsigned int pack_trunc(float lo, float hi){
  union { float f; unsigned int u; } a, b; a.f = lo; b.f = hi;
  return __builtin_amdgcn_perm(b.u, a.u, 0x07060302u);
}

// prep, one dispatch, 3 block-range segments:
//  blk [0,720):    Ws B-frags (layout verified R5/R6) + zero vsum
//  blk [720,1440): Wcc2 per-e B-frags (verified R6)
//  blk [1440,1728): x -> xbf[i][b] bf16 uint4, transposed through LDS so both
//                   global read AND write are coalesced
__global__ __launch_bounds__(256) void caps_prep(
    const float* __restrict__ W, const float* __restrict__ x,
    uint4* __restrict__ wsf, uint4* __restrict__ wcc2,
    uint4* __restrict__ xbf, float* __restrict__ vsum)
{
  __shared__ unsigned int tx[4][64 * 17];   // 17-pad: conflict-light transpose
  const int blk = blockIdx.x, tid = threadIdx.x;
  if (blk < 720) {
    const int t = blk * 256 + tid;          // 0..184319
    if (t < B_N * J_N * D_N) vsum[t] = 0.f;
    const int d  = t & 15;
    const int ji = t >> 4;
    const int i  = ji % IC_N;
    const int j  = ji / IC_N;
    const float4* src = (const float4*)(W + ((size_t)t << 3));
    const float4 a = src[0], b = src[1];
    uint4 q;
    q.x = pack_rne(a.x, a.y); q.y = pack_rne(a.z, a.w);
    q.z = pack_rne(b.x, b.y); q.w = pack_rne(b.z, b.w);
    wsf[(j * 288 + (i >> 2)) * 64 + (i & 3) * 16 + d] = q;
  } else if (blk < 1440) {
    const int t2    = (blk - 720) * 256 + tid;
    const int lane  = t2 & 31;
    const int rest  = t2 >> 5;
    const int itile = rest % 72;
    const int je    = rest / 72;            // 0..79
    const int e     = je & 7;
    const int j     = je >> 3;
    const int i     = itile * 16 + (lane & 15);
    const int dbase = (lane >> 4) * 8;
    const float* src = W + (((size_t)(j * IC_N + i) * D_N + dbase) << 3) + e;
    uint4 q;
    q.x = pack_rne(src[0],  src[8]);  q.y = pack_rne(src[16], src[24]);
    q.z = pack_rne(src[32], src[40]); q.w = pack_rne(src[48], src[56]);
    wcc2[t2] = q;
  } else {
    const int xb = blk - 1440;              // 0..287
    const int b0 = (xb / 18) * 16;
    const int i0 = (xb % 18) * 64;
    #pragma unroll
    for (int r = 0; r < 4; ++r) {
      const int bl = r * 4 + (tid >> 6);
      const int il = tid & 63;
      const float4* sp = (const float4*)(x + ((size_t)((b0 + bl) * IC_N + i0 + il) << 3));
      const float4 a = sp[0], c = sp[1];
      tx[0][il * 17 + bl] = pack_rne(a.x, a.y);
      tx[1][il * 17 + bl] = pack_rne(a.z, a.w);
      tx[2][il * 17 + bl] = pack_rne(c.x, c.y);
      tx[3][il * 17 + bl] = pack_rne(c.z, c.w);
    }
    __syncthreads();
    #pragma unroll
    for (int it = 0; it < 4; ++it) {
      const int p  = it * 256 + tid;
      const int il = p >> 4, bl = p & 15;
      uint4 q;
      q.x = tx[0][il * 17 + bl]; q.y = tx[1][il * 17 + bl];
      q.z = tx[2][il * 17 + bl]; q.w = tx[3][il * 17 + bl];
      xbf[(size_t)(i0 + il) * 256 + b0 + bl] = q;   // 16 lanes x 16B contiguous
    }
  }
}

// Pass: grid (btile 16, chunk 36 of 32 i), block 640 = 10 waves, wave = j.
// Loads explicitly hoisted in batches for MLP (R6 was serial: VGPR=44).
__global__ __launch_bounds__(640, 5) void caps_pass(
    const uint4* __restrict__ xbf,
    const uint4* __restrict__ wsf,
    const uint4* __restrict__ wcc2,
    const uint4* __restrict__ vsbf,     // vsum bf16 A-frag source
    float* __restrict__ s_part,         // [btile16][j10][b16][ch36][d16]
    const int round)
{
  __shared__ float ccl[10 * 32 * 17];   // [j][i_local][b pad17], 21.8 KB

  const int tid  = threadIdx.x;
  const int wave = tid >> 6;            // = j
  const int lane = tid & 63;
  const int quad = lane >> 4;
  const int col  = lane & 15;
  const int b0   = blockIdx.x << 4;
  const int i0   = blockIdx.y << 5;

  if (round > 0) {
    short8 av = {0,0,0,0,0,0,0,0};      // vsum[b=col][d=quad*8+..]; q2,3 K-pad
    if (quad < 2)
      av = *(const short8*)&vsbf[((size_t)(b0 + col) * J_N + wave) * 2 + quad];

    #pragma unroll
    for (int t2 = 0; t2 < 2; ++t2) {
      uint4 bvq[8];                     // hoisted: 8 loads in flight
      #pragma unroll
      for (int e = 0; e < 8; ++e) {
        uint4 q = {0u, 0u, 0u, 0u};
        if (lane < 32)
          q = wcc2[(((size_t)wave * 8 + e) * 72 + (blockIdx.y << 1) + t2) * 32 + lane];
        bvq[e] = q;
      }
      uint4 xr[4];                      // hoisted x[b=quad*4+r][i=col]
      #pragma unroll
      for (int r = 0; r < 4; ++r)
        xr[r] = xbf[(size_t)(i0 + t2 * 16 + col) * 256 + b0 + quad * 4 + r];

      floatx4 cc4 = {0.f, 0.f, 0.f, 0.f};
      #pragma unroll
      for (int e = 0; e < 8; ++e) {
        u4s8 bv; bv.u = bvq[e];
        floatx4 tf = {0.f, 0.f, 0.f, 0.f};
        tf = __builtin_amdgcn_mfma_f32_16x16x32_bf16(av, bv.s, tf, 0, 0, 0);
        #pragma unroll
        for (int r = 0; r < 4; ++r) {
          const unsigned int u = ((const unsigned int*)&xr[r])[e >> 1];
          const float xe = (e & 1) ? bf_hi(u) : bf_lo(u);
          cc4[r] += tf[r] * xe;
        }
      }
      #pragma unroll
      for (int r = 0; r < 4; ++r)
        ccl[(wave * 32 + t2 * 16 + col) * 17 + quad * 4 + r] = cc4[r];
    }
    __syncthreads();
    if (tid < 512) {                    // softmax over j per (i,b), in place
      const int i = tid >> 4, b = tid & 15;
      float cc[10];
      #pragma unroll
      for (int j = 0; j < 10; ++j) cc[j] = ccl[(j * 32 + i) * 17 + b];
      float m = cc[0];
      #pragma unroll
      for (int j = 1; j < 10; ++j) m = fmaxf(m, cc[j]);
      float den = 0.f;
      #pragma unroll
      for (int j = 0; j < 10; ++j) { cc[j] = __expf(cc[j] - m); den += cc[j]; }
      const float rd = __builtin_amdgcn_rcpf(den);
      #pragma unroll
      for (int j = 0; j < 10; ++j) ccl[(j * 32 + i) * 17 + b] = cc[j] * rd;
    }
    __syncthreads();
  }

  // Phase B: s[b,d] += (c*x) @ Ws, K=256; loads in 2 hoisted groups of 4
  floatx4 acc = {0.f, 0.f, 0.f, 0.f};
  #pragma unroll
  for (int g = 0; g < 2; ++g) {
    uint4 xq[4], wf[4];
    float cv[4];
    #pragma unroll
    for (int k = 0; k < 4; ++k) {
      const int kt = g * 4 + k;
      const int il = kt * 4 + quad;
      xq[k] = xbf[(size_t)(i0 + il) * 256 + b0 + col];
      wf[k] = wsf[((size_t)wave * 288 + (blockIdx.y << 3) + kt) * 64 + lane];
      cv[k] = (round > 0) ? ccl[(wave * 32 + il) * 17 + col] : 0.1f;
    }
    #pragma unroll
    for (int k = 0; k < 4; ++k) {
      short8 af;
      unsigned int* aq = (unsigned int*)&af;
      aq[0] = pack_trunc(bf_lo(xq[k].x) * cv[k], bf_hi(xq[k].x) * cv[k]);
      aq[1] = pack_trunc(bf_lo(xq[k].y) * cv[k], bf_hi(xq[k].y) * cv[k]);
      aq[2] = pack_trunc(bf_lo(xq[k].z) * cv[k], bf_hi(xq[k].z) * cv[k]);
      aq[3] = pack_trunc(bf_lo(xq[k].w) * cv[k], bf_hi(xq[k].w) * cv[k]);
      u4s8 bw; bw.u = wf[k];
      acc = __builtin_amdgcn_mfma_f32_16x16x32_bf16(af, bw.s, acc, 0, 0, 0);
    }
  }
  // s_part[btile][j][b=quad*4+r][ch][d=col]
  float* sp = s_part + ((((size_t)blockIdx.x * 10 + wave) * 16 + quad * 4) * 36
                        + blockIdx.y) * 16 + col;
  #pragma unroll
  for (int r = 0; r < 4; ++r) sp[r * 576] = acc[r];
}

// squash: one wave per (b,j); contiguous 576-float run, 9 coalesced loads,
// shuffle-reduced; squash; vsum(fp32)+vsbf(bf16) update or output emit.
// R7 bug fixed here: vsbf must hold the ACCUMULATED v-sum (cc_2 = u.(v0+v1)),
// not just this round's v — pack vt = vsum + v, shuffling vt for the partner.
__global__ __launch_bounds__(256) void caps_squash(
    const float* __restrict__ s_part, float* __restrict__ vsum,
    unsigned int* __restrict__ vsbf_u, float* __restrict__ out, const int round)
{
  const int tid  = threadIdx.x;
  const int w    = tid >> 6;
  const int lane = tid & 63;
  const int bj   = blockIdx.x * 4 + w;            // 0..2559
  const int b    = bj / 10, j = bj - b * 10;
  const int btile = b >> 4, brem = b & 15;
  const float* base = s_part + (((size_t)btile * 10 + j) * 16 + brem) * 576;
  float acc = 0.f;
  #pragma unroll
  for (int q = 0; q < 9; ++q) acc += base[q * 64 + lane];
  acc += __shfl_xor(acc, 16, 64);
  acc += __shfl_xor(acc, 32, 64);                 // sum over ch for d=lane&15
  const float s = acc;
  float sq = s * s;
  sq += __shfl_xor(sq, 1, 16);
  sq += __shfl_xor(sq, 2, 16);
  sq += __shfl_xor(sq, 4, 16);
  sq += __shfl_xor(sq, 8, 16);
  const float coef = (sq / (1.f + sq)) * rsqrtf(sq + 1e-7f);
  const float v = coef * s;
  if (round < 2) {
    const float vprev = (lane < 16) ? vsum[bj * 16 + lane] : 0.f;
    const float vt = vprev + v;                   // accumulated v-sum
    const float vtn = __shfl_down(vt, 1, 64);     // partner d+1 (accumulated)
    if (lane < 16) {
      vsum[bj * 16 + lane] = vt;
      if (!(lane & 1))
        vsbf_u[bj * 8 + (lane >> 1)] = pack_rne(vt, vtn);
    }
  } else if (lane < 16) {
    out[bj * 16 + lane] = v;
  }
}

extern "C" void kernel_launch(void* const* d_in, const int* in_sizes, int n_in,
                              void* d_out, int out_size, void* d_ws, size_t ws_size,
                              hipStream_t stream)
{
  const float* x = (const float*)d_in[0];   // [256][1152][8] fp32
  const float* W = (const float*)d_in[1];   // [10][1152][16][8] fp32

  // ws: Ws 2.95M | Wcc2 2.95M | xbf 4.72M | s_part 5.90M | vsum 164K | vsbf 82K
  uint4* wsf   = (uint4*)d_ws;                        // 184320 uint4
  uint4* wcc2  = wsf + 184320;                        // 184320 uint4
  uint4* xbf   = wcc2 + 184320;                       // 294912 uint4
  float* s_prt = (float*)(xbf + 294912);              // 1474560 f
  float* vsum  = s_prt + 1474560;                     // 40960 f
  unsigned int* vsbf_u = (unsigned int*)(vsum + 40960);

  caps_prep<<<dim3(1728), dim3(256), 0, stream>>>(W, x, wsf, wcc2,
                                                  (uint4*)xbf, vsum);
  for (int r = 0; r < 3; ++r) {
    caps_pass<<<dim3(16, 36), dim3(640), 0, stream>>>(
        xbf, wsf, wcc2, (const uint4*)vsbf_u, s_prt, r);
    caps_squash<<<dim3(640), dim3(256), 0, stream>>>(
        s_prt, vsum, vsbf_u, (float*)d_out, r);
  }
}

// Round 9
// 115.843 us; speedup vs baseline: 3.3384x; 1.1312x over previous
//
#include <hip/hip_runtime.h>

#define B_N 256
#define IC_N 1152
#define J_N 10
#define D_N 16

typedef __attribute__((ext_vector_type(8))) short short8;
typedef __attribute__((ext_vector_type(4))) float floatx4;

union u4s8 { uint4 u; short8 s; };

__device__ __forceinline__ float bf_lo(unsigned int u){
  union { unsigned int i; float f; } c; c.i = u << 16; return c.f;
}
__device__ __forceinline__ float bf_hi(unsigned int u){
  union { unsigned int i; float f; } c; c.i = u & 0xffff0000u; return c.f;
}
__device__ __forceinline__ unsigned int rne16(float f){
  union { float ff; unsigned int i; } c; c.ff = f;
  return (c.i + 0x7FFFu + ((c.i >> 16) & 1u)) >> 16;
}
__device__ __forceinline__ unsigned int pack_rne(float lo, float hi){
  return rne16(lo) | (rne16(hi) << 16);
}
// trunc-to-bf16 pack in 1 op (v_perm)
__device__ __forceinline__ unsigned int pack_trunc(float lo, float hi){
  union { float f; unsigned int u; } a, b; a.f = lo; b.f = hi;
  return __builtin_amdgcn_perm(b.u, a.u, 0x07060302u);
}

// prep: W read ONCE, coalesced, through LDS; emits Ws + Wcc2 frags (layouts
// identical to R6/R8 verified ones). x read once; emits xbf_ib AND xbf_bi.
//  blk [0,720):    (j, itile16) W tile -> wsf + wcc2
//  blk [720,1008): (b-group16, i-group64) x -> xbf_bi (direct) + xbf_ib (LDS
//                  transpose) + vsum zero
__global__ __launch_bounds__(256) void caps_prep(
    const float* __restrict__ W, const float* __restrict__ x,
    uint4* __restrict__ wsf, uint4* __restrict__ wcc2,
    uint4* __restrict__ xbf_ib, uint4* __restrict__ xbf_bi,
    float* __restrict__ vsum)
{
  const int tid = threadIdx.x;
  if (blockIdx.x < 720) {
    __shared__ unsigned int lw[1024];       // W tile, packed bf16 pairs
    const int j = blockIdx.x / 72, itile = blockIdx.x % 72;
    const float4* Wt = (const float4*)(W + ((size_t)(j * IC_N + itile * 16) << 7));
    #pragma unroll
    for (int h = 0; h < 2; ++h) {
      const float4 f = Wt[h * 256 + tid];
      lw[(h * 256 + tid) * 2]     = pack_rne(f.x, f.y);
      lw[(h * 256 + tid) * 2 + 1] = pack_rne(f.z, f.w);
    }
    __syncthreads();
    {  // wsf: thread p -> kt_local=p>>6, lane=p&63 (i_local=kt*4+(lane>>4), d=lane&15)
      const int ktl = tid >> 6, lane = tid & 63;
      const int base = (ktl * 4 + (lane >> 4)) * 64 + (lane & 15) * 4;
      uint4 q;
      q.x = lw[base]; q.y = lw[base + 1]; q.z = lw[base + 2]; q.w = lw[base + 3];
      wsf[((size_t)j * 288 + itile * 4 + ktl) * 64 + lane] = q;
    }
    {  // wcc2: thread p -> e=p>>5, lane2=p&31 (i_local=lane2&15, dbase=(lane2>>4)*8)
      const int e = tid >> 5, lane2 = tid & 31;
      const int il = lane2 & 15, dbase = (lane2 >> 4) * 8;
      unsigned short h[8];
      #pragma unroll
      for (int k = 0; k < 8; ++k) {
        const unsigned int u = lw[il * 64 + (dbase + k) * 4 + (e >> 1)];
        h[k] = (e & 1) ? (unsigned short)(u >> 16) : (unsigned short)(u & 0xffffu);
      }
      uint4 q;
      q.x = h[0] | ((unsigned int)h[1] << 16);
      q.y = h[2] | ((unsigned int)h[3] << 16);
      q.z = h[4] | ((unsigned int)h[5] << 16);
      q.w = h[6] | ((unsigned int)h[7] << 16);
      wcc2[(((size_t)j * 8 + e) * 72 + itile) * 32 + lane2] = q;
    }
  } else {
    __shared__ unsigned int tx[4][64 * 17];
    const int xb = blockIdx.x - 720;        // 0..287
    const int t0 = xb * 256 + tid;
    if (t0 < B_N * J_N * D_N) vsum[t0] = 0.f;
    const int b0 = (xb / 18) * 16;
    const int i0 = (xb % 18) * 64;
    #pragma unroll
    for (int r = 0; r < 4; ++r) {
      const int bl = r * 4 + (tid >> 6);
      const int il = tid & 63;
      const float4* sp = (const float4*)(x + ((size_t)((b0 + bl) * IC_N + i0 + il) << 3));
      const float4 a = sp[0], c = sp[1];
      uint4 q;
      q.x = pack_rne(a.x, a.y); q.y = pack_rne(a.z, a.w);
      q.z = pack_rne(c.x, c.y); q.w = pack_rne(c.z, c.w);
      xbf_bi[(size_t)(b0 + bl) * IC_N + i0 + il] = q;   // 64 lanes x 16B contiguous
      tx[0][il * 17 + bl] = q.x; tx[1][il * 17 + bl] = q.y;
      tx[2][il * 17 + bl] = q.z; tx[3][il * 17 + bl] = q.w;
    }
    __syncthreads();
    #pragma unroll
    for (int it = 0; it < 4; ++it) {
      const int p  = it * 256 + tid;
      const int il = p >> 4, bl = p & 15;
      uint4 q;
      q.x = tx[0][il * 17 + bl]; q.y = tx[1][il * 17 + bl];
      q.z = tx[2][il * 17 + bl]; q.w = tx[3][il * 17 + bl];
      xbf_ib[(size_t)(i0 + il) * 256 + b0 + bl] = q;
    }
  }
}

// Pass: grid (btile 16, chunk 72 of 16 i), block 640 = 10 waves, wave = j.
// Phase A reads x from xbf_bi (lanes=i contiguous), phase B from xbf_ib
// (lanes=b contiguous) — all x loads are 256B-run coalesced now.
__global__ __launch_bounds__(640, 5) void caps_pass(
    const uint4* __restrict__ xbf_ib,
    const uint4* __restrict__ xbf_bi,
    const uint4* __restrict__ wsf,
    const uint4* __restrict__ wcc2,
    const uint4* __restrict__ vsbf,
    float* __restrict__ s_part,         // [btile16][j10][b16][ch72][d16]
    const int round)
{
  __shared__ float ccl[10 * 16 * 17];   // [j][i_local][b pad17], 10.6 KB

  const int tid  = threadIdx.x;
  const int wave = tid >> 6;            // = j
  const int lane = tid & 63;
  const int quad = lane >> 4;
  const int col  = lane & 15;
  const int b0   = blockIdx.x << 4;
  const int i0   = blockIdx.y << 4;     // 16 i per chunk

  if (round > 0) {
    short8 av = {0,0,0,0,0,0,0,0};      // vsum[b=col][d=quad*8+..]; q2,3 K-pad
    if (quad < 2)
      av = *(const short8*)&vsbf[((size_t)(b0 + col) * J_N + wave) * 2 + quad];

    uint4 bvq[8];                       // hoisted: 8 loads in flight
    #pragma unroll
    for (int e = 0; e < 8; ++e) {
      uint4 q = {0u, 0u, 0u, 0u};
      if (lane < 32)
        q = wcc2[(((size_t)wave * 8 + e) * 72 + blockIdx.y) * 32 + lane];
      bvq[e] = q;
    }
    uint4 xr[4];                        // x[b=quad*4+r][i=col], coalesced
    #pragma unroll
    for (int r = 0; r < 4; ++r)
      xr[r] = xbf_bi[(size_t)(b0 + quad * 4 + r) * IC_N + i0 + col];

    floatx4 cc4 = {0.f, 0.f, 0.f, 0.f};
    #pragma unroll
    for (int e = 0; e < 8; ++e) {
      u4s8 bv; bv.u = bvq[e];
      floatx4 tf = {0.f, 0.f, 0.f, 0.f};
      tf = __builtin_amdgcn_mfma_f32_16x16x32_bf16(av, bv.s, tf, 0, 0, 0);
      #pragma unroll
      for (int r = 0; r < 4; ++r) {
        const unsigned int u = ((const unsigned int*)&xr[r])[e >> 1];
        const float xe = (e & 1) ? bf_hi(u) : bf_lo(u);
        cc4[r] += tf[r] * xe;
      }
    }
    #pragma unroll
    for (int r = 0; r < 4; ++r)
      ccl[(wave * 16 + col) * 17 + quad * 4 + r] = cc4[r];
    __syncthreads();
    if (tid < 256) {                    // softmax over j per (i,b), in place
      const int i = tid >> 4, b = tid & 15;
      float cc[10];
      #pragma unroll
      for (int j = 0; j < 10; ++j) cc[j] = ccl[(j * 16 + i) * 17 + b];
      float m = cc[0];
      #pragma unroll
      for (int j = 1; j < 10; ++j) m = fmaxf(m, cc[j]);
      float den = 0.f;
      #pragma unroll
      for (int j = 0; j < 10; ++j) { cc[j] = __expf(cc[j] - m); den += cc[j]; }
      const float rd = __builtin_amdgcn_rcpf(den);
      #pragma unroll
      for (int j = 0; j < 10; ++j) ccl[(j * 16 + i) * 17 + b] = cc[j] * rd;
    }
    __syncthreads();
  }

  // Phase B: s[b,d] += (c*x) @ Ws, K=128 (4 k-tiles), loads hoisted
  floatx4 acc = {0.f, 0.f, 0.f, 0.f};
  uint4 xq[4], wf[4];
  float cv[4];
  #pragma unroll
  for (int kt = 0; kt < 4; ++kt) {
    const int il = kt * 4 + quad;
    xq[kt] = xbf_ib[(size_t)(i0 + il) * 256 + b0 + col];
    wf[kt] = wsf[((size_t)wave * 288 + (blockIdx.y << 2) + kt) * 64 + lane];
    cv[kt] = (round > 0) ? ccl[(wave * 16 + il) * 17 + col] : 0.1f;
  }
  #pragma unroll
  for (int kt = 0; kt < 4; ++kt) {
    short8 af;
    unsigned int* aq = (unsigned int*)&af;
    aq[0] = pack_trunc(bf_lo(xq[kt].x) * cv[kt], bf_hi(xq[kt].x) * cv[kt]);
    aq[1] = pack_trunc(bf_lo(xq[kt].y) * cv[kt], bf_hi(xq[kt].y) * cv[kt]);
    aq[2] = pack_trunc(bf_lo(xq[kt].z) * cv[kt], bf_hi(xq[kt].z) * cv[kt]);
    aq[3] = pack_trunc(bf_lo(xq[kt].w) * cv[kt], bf_hi(xq[kt].w) * cv[kt]);
    u4s8 bw; bw.u = wf[kt];
    acc = __builtin_amdgcn_mfma_f32_16x16x32_bf16(af, bw.s, acc, 0, 0, 0);
  }
  // s_part[btile][j][b=quad*4+r][ch][d=col]
  float* sp = s_part + ((((size_t)blockIdx.x * 10 + wave) * 16 + quad * 4) * 72
                        + blockIdx.y) * 16 + col;
  #pragma unroll
  for (int r = 0; r < 4; ++r) sp[(size_t)r * 72 * 16] = acc[r];
}

// squash: one wave per (b,j); 1152 contiguous floats, 18 coalesced loads,
// shuffle-reduced; vsbf holds ACCUMULATED v-sum (R7 lesson).
__global__ __launch_bounds__(256) void caps_squash(
    const float* __restrict__ s_part, float* __restrict__ vsum,
    unsigned int* __restrict__ vsbf_u, float* __restrict__ out, const int round)
{
  const int tid  = threadIdx.x;
  const int w    = tid >> 6;
  const int lane = tid & 63;
  const int bj   = blockIdx.x * 4 + w;            // 0..2559
  const int b    = bj / 10, j = bj - b * 10;
  const int btile = b >> 4, brem = b & 15;
  const float* base = s_part + (((size_t)btile * 10 + j) * 16 + brem) * 1152;
  float acc = 0.f;
  #pragma unroll
  for (int q = 0; q < 18; ++q) acc += base[q * 64 + lane];
  acc += __shfl_xor(acc, 16, 64);
  acc += __shfl_xor(acc, 32, 64);                 // sum over ch for d=lane&15
  const float s = acc;
  float sq = s * s;
  sq += __shfl_xor(sq, 1, 16);
  sq += __shfl_xor(sq, 2, 16);
  sq += __shfl_xor(sq, 4, 16);
  sq += __shfl_xor(sq, 8, 16);
  const float coef = (sq / (1.f + sq)) * rsqrtf(sq + 1e-7f);
  const float v = coef * s;
  if (round < 2) {
    const float vprev = (lane < 16) ? vsum[bj * 16 + lane] : 0.f;
    const float vt = vprev + v;                   // accumulated v-sum
    const float vtn = __shfl_down(vt, 1, 64);
    if (lane < 16) {
      vsum[bj * 16 + lane] = vt;
      if (!(lane & 1))
        vsbf_u[bj * 8 + (lane >> 1)] = pack_rne(vt, vtn);
    }
  } else if (lane < 16) {
    out[bj * 16 + lane] = v;
  }
}

extern "C" void kernel_launch(void* const* d_in, const int* in_sizes, int n_in,
                              void* d_out, int out_size, void* d_ws, size_t ws_size,
                              hipStream_t stream)
{
  const float* x = (const float*)d_in[0];   // [256][1152][8] fp32
  const float* W = (const float*)d_in[1];   // [10][1152][16][8] fp32

  // ws: wsf 2.95M | wcc2 2.95M | xbf_ib 4.72M | xbf_bi 4.72M | s_part 11.8M
  //     | vsum 164K | vsbf 82K   (~27.3 MB)
  uint4* wsf    = (uint4*)d_ws;                       // 184320 uint4
  uint4* wcc2   = wsf + 184320;                       // 184320 uint4
  uint4* xbf_ib = wcc2 + 184320;                      // 294912 uint4
  uint4* xbf_bi = xbf_ib + 294912;                    // 294912 uint4
  float* s_prt  = (float*)(xbf_bi + 294912);          // 2949120 f
  float* vsum   = s_prt + 2949120;                    // 40960 f
  unsigned int* vsbf_u = (unsigned int*)(vsum + 40960);

  caps_prep<<<dim3(1008), dim3(256), 0, stream>>>(W, x, wsf, wcc2,
                                                  xbf_ib, xbf_bi, vsum);
  for (int r = 0; r < 3; ++r) {
    caps_pass<<<dim3(16, 72), dim3(640), 0, stream>>>(
        xbf_ib, xbf_bi, wsf, wcc2, (const uint4*)vsbf_u, s_prt, r);
    caps_squash<<<dim3(640), dim3(256), 0, stream>>>(
        s_prt, vsum, vsbf_u, (float*)d_out, r);
  }
}